// Round 7
// baseline (837.949 us; speedup 1.0000x reference)
//
#include <hip/hip_runtime.h>

#define NX 512
#define NY 512
#define NZ 256

typedef float v4f __attribute__((ext_vector_type(4)));

// One point per thread. Per point: 4 independent 16B gathers (z-pair fused),
// branchless validity (invalid lanes alias index 0 -> one cached line),
// coalesced x reads and out writes.
__global__ __launch_bounds__(256) void trilerp_kernel(
    const float* __restrict__ x,
    const float* __restrict__ grid,
    const float* __restrict__ lower,
    const float* __restrict__ resolution,
    float* __restrict__ out,
    int n)
{
    int i = blockIdx.x * blockDim.x + threadIdx.x;
    if (i >= n) return;

    float px = x[3 * i + 0];
    float py = x[3 * i + 1];
    float pz = x[3 * i + 2];

    float fx = (px - lower[0]) * resolution[0];
    float fy = (py - lower[1]) * resolution[1];
    float fz = (pz - lower[2]) * resolution[2];

    bool valid = (fx >= 0.0f) && (fx <= (float)(NX - 1)) &&
                 (fy >= 0.0f) && (fy <= (float)(NY - 1)) &&
                 (fz >= 0.0f) && (fz <= (float)(NZ - 1));

    // Clamp base so corner+1 is in-bounds and the z-pair is contiguous.
    // wx = fx - ix0 reproduces the reference's clamped interpolation exactly
    // (fx == NX-1 -> ix0 = NX-2, wx = 1.0 -> selects plane NX-1).
    int ix0 = min(max((int)floorf(fx), 0), NX - 2);
    int iy0 = min(max((int)floorf(fy), 0), NY - 2);
    int iz0 = min(max((int)floorf(fz), 0), NZ - 2);
    float wx = fx - (float)ix0;
    float wy = fy - (float)iy0;
    float wz = fz - (float)iz0;

    int row0 = (ix0 * NY + iy0) * NZ + iz0;
    int b00 = valid ? row0 : 0;
    int b01 = valid ? row0 + NZ : 0;
    int b10 = valid ? row0 + NY * NZ : 0;
    int b11 = valid ? row0 + NY * NZ + NZ : 0;

    const float2* __restrict__ g = (const float2*)grid;

    // 4 independent 16B loads: {sigma(z0), alpha(z0), sigma(z1), alpha(z1)}
    v4f v00, v01, v10, v11;
    __builtin_memcpy(&v00, g + b00, 16);
    __builtin_memcpy(&v01, g + b01, 16);
    __builtin_memcpy(&v10, g + b10, 16);
    __builtin_memcpy(&v11, g + b11, 16);

    float uz = 1.0f - wz, uy = 1.0f - wy, ux = 1.0f - wx;
    float s00 = v00.x * uz + v00.z * wz;
    float a00 = v00.y * uz + v00.w * wz;
    float s01 = v01.x * uz + v01.z * wz;
    float a01 = v01.y * uz + v01.w * wz;
    float s10 = v10.x * uz + v10.z * wz;
    float a10 = v10.y * uz + v10.w * wz;
    float s11 = v11.x * uz + v11.z * wz;
    float a11 = v11.y * uz + v11.w * wz;

    float sigma = ux * (uy * s00 + wy * s01) + wx * (uy * s10 + wy * s11);
    float alpha = ux * (uy * a00 + wy * a01) + wx * (uy * a10 + wy * a11);

    if (!valid) { sigma = 0.0f; alpha = 0.0f; }

    out[i] = sigma;
    out[n + i] = alpha;
}

extern "C" void kernel_launch(void* const* d_in, const int* in_sizes, int n_in,
                              void* d_out, int out_size, void* d_ws, size_t ws_size,
                              hipStream_t stream) {
    const float* x          = (const float*)d_in[0];
    const float* grid       = (const float*)d_in[1];
    const float* lower      = (const float*)d_in[2];
    const float* resolution = (const float*)d_in[3];
    float* out              = (float*)d_out;

    int n = in_sizes[0] / 3;  // x is [N,3]
    int block = 256;
    int blocks = (n + block - 1) / block;

    // DECOMPOSITION EXPERIMENT: run the identical (idempotent) kernel twice.
    // dur_us(this) - dur_us(single) = marginal cost of one warm-cache
    // execution, separating harness restore/poison overhead from kernel time.
    trilerp_kernel<<<blocks, block, 0, stream>>>(x, grid, lower, resolution, out, n);
    trilerp_kernel<<<blocks, block, 0, stream>>>(x, grid, lower, resolution, out, n);
}

// Round 8
// 716.611 us; speedup vs baseline: 1.1693x; 1.1693x over previous
//
#include <hip/hip_runtime.h>

#define NX 512
#define NY 512
#define NZ 256

typedef float v4f __attribute__((ext_vector_type(4)));

// One point per thread. Per point: 4 independent 16B gathers (z-pair fused),
// branchless validity (invalid lanes alias index 0 -> one cached line),
// coalesced x reads and out writes.
//
// Measured decomposition (R7 double-launch): kernel ≈ 120 µs at 2.6-2.8 TB/s
// effective — the random-gather DRAM-efficiency roofline (working set ~300-430
// MB > 256 MiB L3, no reuse). Instruction count (R0 vs R3), per-thread MLP
// (R1), and spatial sorting (R2) all measured null or negative. Remaining
// dur_us (~598 µs) is the harness's timed restore/poison floor.
__global__ __launch_bounds__(256) void trilerp_kernel(
    const float* __restrict__ x,
    const float* __restrict__ grid,
    const float* __restrict__ lower,
    const float* __restrict__ resolution,
    float* __restrict__ out,
    int n)
{
    int i = blockIdx.x * blockDim.x + threadIdx.x;
    if (i >= n) return;

    float px = x[3 * i + 0];
    float py = x[3 * i + 1];
    float pz = x[3 * i + 2];

    float fx = (px - lower[0]) * resolution[0];
    float fy = (py - lower[1]) * resolution[1];
    float fz = (pz - lower[2]) * resolution[2];

    bool valid = (fx >= 0.0f) && (fx <= (float)(NX - 1)) &&
                 (fy >= 0.0f) && (fy <= (float)(NY - 1)) &&
                 (fz >= 0.0f) && (fz <= (float)(NZ - 1));

    // Clamp base so corner+1 is in-bounds and the z-pair is contiguous.
    // wx = fx - ix0 reproduces the reference's clamped interpolation exactly
    // (fx == NX-1 -> ix0 = NX-2, wx = 1.0 -> selects plane NX-1).
    int ix0 = min(max((int)floorf(fx), 0), NX - 2);
    int iy0 = min(max((int)floorf(fy), 0), NY - 2);
    int iz0 = min(max((int)floorf(fz), 0), NZ - 2);
    float wx = fx - (float)ix0;
    float wy = fy - (float)iy0;
    float wz = fz - (float)iz0;

    int row0 = (ix0 * NY + iy0) * NZ + iz0;
    int b00 = valid ? row0 : 0;
    int b01 = valid ? row0 + NZ : 0;
    int b10 = valid ? row0 + NY * NZ : 0;
    int b11 = valid ? row0 + NY * NZ + NZ : 0;

    const float2* __restrict__ g = (const float2*)grid;

    // 4 independent 16B loads: {sigma(z0), alpha(z0), sigma(z1), alpha(z1)}
    v4f v00, v01, v10, v11;
    __builtin_memcpy(&v00, g + b00, 16);
    __builtin_memcpy(&v01, g + b01, 16);
    __builtin_memcpy(&v10, g + b10, 16);
    __builtin_memcpy(&v11, g + b11, 16);

    float uz = 1.0f - wz, uy = 1.0f - wy, ux = 1.0f - wx;
    float s00 = v00.x * uz + v00.z * wz;
    float a00 = v00.y * uz + v00.w * wz;
    float s01 = v01.x * uz + v01.z * wz;
    float a01 = v01.y * uz + v01.w * wz;
    float s10 = v10.x * uz + v10.z * wz;
    float a10 = v10.y * uz + v10.w * wz;
    float s11 = v11.x * uz + v11.z * wz;
    float a11 = v11.y * uz + v11.w * wz;

    float sigma = ux * (uy * s00 + wy * s01) + wx * (uy * s10 + wy * s11);
    float alpha = ux * (uy * a00 + wy * a01) + wx * (uy * a10 + wy * a11);

    if (!valid) { sigma = 0.0f; alpha = 0.0f; }

    out[i] = sigma;
    out[n + i] = alpha;
}

extern "C" void kernel_launch(void* const* d_in, const int* in_sizes, int n_in,
                              void* d_out, int out_size, void* d_ws, size_t ws_size,
                              hipStream_t stream) {
    const float* x          = (const float*)d_in[0];
    const float* grid       = (const float*)d_in[1];
    const float* lower      = (const float*)d_in[2];
    const float* resolution = (const float*)d_in[3];
    float* out              = (float*)d_out;

    int n = in_sizes[0] / 3;  // x is [N,3]
    int block = 256;
    int blocks = (n + block - 1) / block;
    trilerp_kernel<<<blocks, block, 0, stream>>>(x, grid, lower, resolution, out, n);
}